// Round 12
// baseline (328.491 us; speedup 1.0000x reference)
//
#include <hip/hip_runtime.h>
#include <hip/hip_bf16.h>

#define D 128
#define NGRAPH 64
#define POOLBLK 256     // blocks in k_pool_edges
#define PBCHUNK 4096    // edges per block in k_part
#define WINSZ 256       // nodes per dst-window
#define WINSLOTS 16384  // edge slots per window (mean ~8184, 2x headroom)
#define XP 136          // padded LDS row (bf16) -> 2-way bank aliasing only
#define GBM 128         // gemm row tile

typedef __attribute__((ext_vector_type(4))) float f32x4;
typedef __attribute__((ext_vector_type(8))) short bf16x8;

__device__ __forceinline__ unsigned short f2bf(float f) {
    union { float f; unsigned int i; } u; u.f = f;
    unsigned int r = u.i + 0x7fffu + ((u.i >> 16) & 1u);   // round-to-nearest-even
    return (unsigned short)(r >> 16);
}
__device__ __forceinline__ float2 bf2_to_f2(unsigned int u) {
    union { unsigned int i; float f; } a, b;
    a.i = u << 16;            // low ushort  = element 0
    b.i = u & 0xffff0000u;    // high ushort = element 1
    return make_float2(a.f, b.f);
}

// ---------------- prep: Weff = W2@Wc, beff, W1bfT (bf16, transposed) -----

__global__ __launch_bounds__(256) void k_prep(const float* __restrict__ W1,
                                              const float* __restrict__ W2,
                                              const float* __restrict__ Wc,
                                              const float* __restrict__ b2,
                                              const float* __restrict__ bc,
                                              float* __restrict__ Weff,
                                              float* __restrict__ beff,
                                              unsigned short* __restrict__ W1bfT) {
    int t = threadIdx.x;
    int i = t >> 1, c = t & 1;
    float a0 = 0.f, a1 = 0.f, a2 = 0.f, a3 = 0.f, a4 = 0.f, a5 = 0.f, a6 = 0.f, a7 = 0.f;
    for (int k = 0; k < D; k += 8) {
        a0 += W2[i * D + k + 0] * Wc[(k + 0) * 2 + c];
        a1 += W2[i * D + k + 1] * Wc[(k + 1) * 2 + c];
        a2 += W2[i * D + k + 2] * Wc[(k + 2) * 2 + c];
        a3 += W2[i * D + k + 3] * Wc[(k + 3) * 2 + c];
        a4 += W2[i * D + k + 4] * Wc[(k + 4) * 2 + c];
        a5 += W2[i * D + k + 5] * Wc[(k + 5) * 2 + c];
        a6 += W2[i * D + k + 6] * Wc[(k + 6) * 2 + c];
        a7 += W2[i * D + k + 7] * Wc[(k + 7) * 2 + c];
    }
    Weff[i * 2 + c] = ((a0 + a1) + (a2 + a3)) + ((a4 + a5) + (a6 + a7));
    if (i == 0) {
        float s0 = 0.f, s1 = 0.f, s2 = 0.f, s3 = 0.f;
        for (int k = 0; k < D; k += 4) {
            s0 += b2[k + 0] * Wc[(k + 0) * 2 + c];
            s1 += b2[k + 1] * Wc[(k + 1) * 2 + c];
            s2 += b2[k + 2] * Wc[(k + 2) * 2 + c];
            s3 += b2[k + 3] * Wc[(k + 3) * 2 + c];
        }
        beff[c] = (s0 + s1) + (s2 + s3) + bc[c];
    }
    // transpose-convert W1: coalesced read W1[k][n], scattered u16 write
    for (int e = t; e < D * D; e += 256) {
        int k = e >> 7, nn = e & 127;
        W1bfT[nn * D + k] = f2bf(W1[k * D + nn]);
    }
}

// ---------------- CSR build: windowed counting sort ----------------------
// phase 1: count bins; phase 2: re-read edges (L2-hot), assign slot, scatter.

__global__ __launch_bounds__(256) void k_part(const int* __restrict__ src,
                                              const int* __restrict__ dst,
                                              int* __restrict__ cursor,
                                              unsigned* __restrict__ ebuf,
                                              int E, int nb) {
    __shared__ int hist[400];
    __shared__ int hist2[400];
    __shared__ int base[400];
    int tid = threadIdx.x;
    for (int i = tid; i < nb; i += 256) { hist[i] = 0; hist2[i] = 0; }
    __syncthreads();
    int b0 = blockIdx.x * PBCHUNK;
    int cnt = min(PBCHUNK, E - b0);
    for (int j = tid; j < cnt; j += 256) {
        int d = __builtin_nontemporal_load(&dst[b0 + j]);
        atomicAdd(&hist[d >> 8], 1);
    }
    __syncthreads();
    for (int i = tid; i < nb; i += 256)
        base[i] = hist[i] ? atomicAdd(&cursor[i], hist[i]) : 0;
    __syncthreads();
    for (int j = tid; j < cnt; j += 256) {
        int s = src[b0 + j];
        int d = dst[b0 + j];
        int bin = d >> 8;
        int pos = base[bin] + atomicAdd(&hist2[bin], 1);
        ebuf[(size_t)bin * WINSLOTS + pos] = (unsigned)s | ((unsigned)(d & 255) << 17);
    }
}

__global__ __launch_bounds__(256) void k_csrwin(const unsigned* __restrict__ ebuf,
                                                const int* __restrict__ cursor,
                                                int* __restrict__ csr,
                                                int2* __restrict__ offcnt,
                                                float* __restrict__ dinv, int n) {
    __shared__ int hist[WINSZ];
    __shared__ int lscan[WINSZ];
    __shared__ int sexcl[WINSZ];
    int b = blockIdx.x;
    int tid = threadIdx.x;
    hist[tid] = 0;
    __syncthreads();
    int cnt = cursor[b];
    const unsigned* eb = ebuf + (size_t)b * WINSLOTS;
    for (int j = tid; j < cnt; j += 256)
        atomicAdd(&hist[eb[j] >> 17], 1);
    __syncthreads();
    int deg = hist[tid];
    lscan[tid] = deg;
    __syncthreads();
    for (int off = 1; off < 256; off <<= 1) {
        int y = (tid >= off) ? lscan[tid - off] : 0;
        __syncthreads();
        lscan[tid] += y;
        __syncthreads();
    }
    int excl = lscan[tid] - deg;
    int v = b * WINSZ + tid;
    int gbase = b * WINSLOTS;
    if (v < n) {
        offcnt[v] = make_int2(gbase + excl, deg);
        dinv[v] = rsqrtf((float)(deg + 1));
    }
    hist[tid] = 0;
    sexcl[tid] = excl;
    __syncthreads();
    for (int j = tid; j < cnt; j += 256) {
        unsigned p = eb[j];
        int d8 = (int)(p >> 17);
        int lr = atomicAdd(&hist[d8], 1);
        csr[gbase + sexcl[d8] + lr] = (int)(p & 0x1FFFFu);
    }
}

// ---------------- MFMA bf16 GEMM: H = bf16(X) @ bf16(W1), bf16 out ------
// BM=128 rows/block, W from prepped W1bfT (coalesced stage).
// A frag (16x16x32): lane l -> row=l&15, k=8*(l>>4)+j ; B: col=l&15, k same
// C/D: col=lane&15, row=4*(lane>>4)+reg   [m89-verified]

__global__ __launch_bounds__(256) void k_gemm_mfma(const float* __restrict__ X,
                                                   const unsigned short* __restrict__ W1bfT,
                                                   unsigned short* __restrict__ H, int nrows) {
    __shared__ unsigned short xs[GBM][XP];   // X tile, bf16
    __shared__ unsigned short wt[128][XP];   // W^T: wt[n][k]
    int tid = threadIdx.x;
    int m0 = blockIdx.x * GBM;
    // stage W^T coalesced (2048 uint4)
    {
        const uint4* wsrc = (const uint4*)W1bfT;
        for (int i = tid; i < 2048; i += 256) {
            uint4 v = wsrc[i];
            int elt = i * 8;
            int r = elt >> 7, c = elt & 127;
            *(uint4*)&wt[r][c] = v;
        }
    }
    // stage X tile (convert fp32 -> bf16), 4096 float4
    {
        for (int i = tid; i < 4096; i += 256) {
            int elt = i * 4;
            int r = elt >> 7, c = elt & 127;
            int gr = m0 + r;
            float4 v = (gr < nrows) ? *(const float4*)&X[(size_t)gr * D + c]
                                    : make_float4(0.f, 0.f, 0.f, 0.f);
            ushort4 bv;
            bv.x = f2bf(v.x); bv.y = f2bf(v.y); bv.z = f2bf(v.z); bv.w = f2bf(v.w);
            *(ushort4*)&xs[r][c] = bv;
        }
    }
    __syncthreads();
    int wv = tid >> 6, lane = tid & 63;
    int lrow = lane & 15, lk = (lane >> 4) * 8;
    f32x4 acc[2][8];
#pragma unroll
    for (int mt = 0; mt < 2; ++mt)
#pragma unroll
        for (int i = 0; i < 8; ++i) acc[mt][i] = (f32x4){0.f, 0.f, 0.f, 0.f};
#pragma unroll
    for (int kk = 0; kk < 128; kk += 32) {
        bf16x8 a0 = *(bf16x8*)&xs[wv * 32 + lrow][kk + lk];
        bf16x8 a1 = *(bf16x8*)&xs[wv * 32 + 16 + lrow][kk + lk];
#pragma unroll
        for (int nt = 0; nt < 8; ++nt) {
            bf16x8 b = *(bf16x8*)&wt[nt * 16 + lrow][kk + lk];
            acc[0][nt] = __builtin_amdgcn_mfma_f32_16x16x32_bf16(a0, b, acc[0][nt], 0, 0, 0);
            acc[1][nt] = __builtin_amdgcn_mfma_f32_16x16x32_bf16(a1, b, acc[1][nt], 0, 0, 0);
        }
    }
#pragma unroll
    for (int mt = 0; mt < 2; ++mt) {
        int orow = m0 + wv * 32 + mt * 16 + (lane >> 4) * 4;
#pragma unroll
        for (int nt = 0; nt < 8; ++nt) {
#pragma unroll
            for (int r = 0; r < 4; ++r) {
                int gr = orow + r;
                if (gr < nrows) H[(size_t)gr * D + nt * 16 + lrow] = f2bf(acc[mt][nt][r]);
            }
        }
    }
}

// ---------------- layer-1 agg + relu + 2-dim projection (8-deep ILP) -----

__global__ __launch_bounds__(256) void k_agg_proj(const unsigned short* __restrict__ H,
                                                  const int2* __restrict__ offcnt,
                                                  const int* __restrict__ csr,
                                                  const float* __restrict__ dinv,
                                                  const float* __restrict__ bias,
                                                  const float* __restrict__ Weff,
                                                  float2* __restrict__ z, int n) {
    int wid = threadIdx.x >> 6;
    int lane = threadIdx.x & 63;
    int v = blockIdx.x * 4 + wid;
    if (v >= n) return;
    float dv = dinv[v];
    int l2 = lane * 2;
    unsigned us = *(const unsigned*)(H + (size_t)v * D + l2);
    float2 hs = bf2_to_f2(us);
    float dv2 = dv * dv;
    float2 acc = make_float2(hs.x * dv2, hs.y * dv2);
    int2 oc = offcnt[v];
    int e = oc.x, eE = oc.x + oc.y;
    for (; e + 7 < eE; e += 8) {
        int s[8];
#pragma unroll
        for (int j = 0; j < 8; ++j) s[j] = csr[e + j];
        unsigned u[8];
#pragma unroll
        for (int j = 0; j < 8; ++j) u[j] = *(const unsigned*)(H + (size_t)s[j] * D + l2);
        float w[8];
#pragma unroll
        for (int j = 0; j < 8; ++j) w[j] = dinv[s[j]] * dv;
#pragma unroll
        for (int j = 0; j < 8; ++j) {
            float2 h = bf2_to_f2(u[j]);
            acc.x += h.x * w[j]; acc.y += h.y * w[j];
        }
    }
    for (; e + 3 < eE; e += 4) {
        int s0 = csr[e], s1 = csr[e + 1], s2 = csr[e + 2], s3 = csr[e + 3];
        unsigned u0 = *(const unsigned*)(H + (size_t)s0 * D + l2);
        unsigned u1 = *(const unsigned*)(H + (size_t)s1 * D + l2);
        unsigned u2 = *(const unsigned*)(H + (size_t)s2 * D + l2);
        unsigned u3 = *(const unsigned*)(H + (size_t)s3 * D + l2);
        float w0 = dinv[s0] * dv, w1 = dinv[s1] * dv;
        float w2 = dinv[s2] * dv, w3 = dinv[s3] * dv;
        float2 h0 = bf2_to_f2(u0), h1 = bf2_to_f2(u1);
        float2 h2 = bf2_to_f2(u2), h3 = bf2_to_f2(u3);
        acc.x += h0.x * w0; acc.y += h0.y * w0;
        acc.x += h1.x * w1; acc.y += h1.y * w1;
        acc.x += h2.x * w2; acc.y += h2.y * w2;
        acc.x += h3.x * w3; acc.y += h3.y * w3;
    }
    for (; e < eE; ++e) {
        int s0 = csr[e];
        float w0 = dinv[s0] * dv;
        unsigned u0 = *(const unsigned*)(H + (size_t)s0 * D + l2);
        float2 h0 = bf2_to_f2(u0);
        acc.x += h0.x * w0; acc.y += h0.y * w0;
    }
    float2 b = ((const float2*)bias)[lane];
    acc.x = fmaxf(acc.x + b.x, 0.f);
    acc.y = fmaxf(acc.y + b.y, 0.f);
    float4 wv = *(const float4*)&Weff[l2 * 2];
    float z0 = acc.x * wv.x + acc.y * wv.z;
    float z1 = acc.x * wv.y + acc.y * wv.w;
#pragma unroll
    for (int off = 32; off >= 1; off >>= 1) {
        z0 += __shfl_xor(z0, off, 64);
        z1 += __shfl_xor(z1, off, 64);
    }
    if (lane == 0) z[v] = make_float2(z0, z1);
}

// ---------------- fused layer-2 agg + mean-pool on projected z -----------

__global__ __launch_bounds__(256) void k_pool_edges(const float2* __restrict__ z,
                                                    const int* __restrict__ src,
                                                    const int* __restrict__ dst,
                                                    const float* __restrict__ dinv,
                                                    const int* __restrict__ batch,
                                                    float* __restrict__ tsum,
                                                    int* __restrict__ cnt,
                                                    int n, int E) {
    __shared__ float t[4][NGRAPH * 2];
    __shared__ int scnt[4][NGRAPH];
    int tid = threadIdx.x;
    int wv = tid >> 6;
    for (int j = tid; j < 4 * NGRAPH * 2; j += 256) ((float*)t)[j] = 0.f;
    for (int j = tid; j < 4 * NGRAPH; j += 256) ((int*)scnt)[j] = 0;
    __syncthreads();

    int i = (blockIdx.x * 256 + tid) * 4;
    int stride = POOLBLK * 256 * 4;
    for (; i < E; i += stride) {
        if (i + 3 < E) {
            int4 s4 = *(const int4*)&src[i];
            int4 d4 = *(const int4*)&dst[i];
            float w0 = dinv[s4.x] * dinv[d4.x];
            float w1 = dinv[s4.y] * dinv[d4.y];
            float w2 = dinv[s4.z] * dinv[d4.z];
            float w3 = dinv[s4.w] * dinv[d4.w];
            float2 z0 = z[s4.x], z1 = z[s4.y], z2 = z[s4.z], z3 = z[s4.w];
            int g0 = batch[d4.x], g1 = batch[d4.y], g2 = batch[d4.z], g3 = batch[d4.w];
            atomicAdd(&t[wv][g0 * 2],     w0 * z0.x);
            atomicAdd(&t[wv][g0 * 2 + 1], w0 * z0.y);
            atomicAdd(&t[wv][g1 * 2],     w1 * z1.x);
            atomicAdd(&t[wv][g1 * 2 + 1], w1 * z1.y);
            atomicAdd(&t[wv][g2 * 2],     w2 * z2.x);
            atomicAdd(&t[wv][g2 * 2 + 1], w2 * z2.y);
            atomicAdd(&t[wv][g3 * 2],     w3 * z3.x);
            atomicAdd(&t[wv][g3 * 2 + 1], w3 * z3.y);
        } else {
            for (int j = i; j < E; ++j) {
                int s = src[j], d = dst[j];
                float w = dinv[s] * dinv[d];
                float2 zv = z[s];
                int g = batch[d];
                atomicAdd(&t[wv][g * 2],     w * zv.x);
                atomicAdd(&t[wv][g * 2 + 1], w * zv.y);
            }
        }
    }
    for (int v = blockIdx.x * 256 + tid; v < n; v += POOLBLK * 256) {
        float dv = dinv[v];
        float2 zv = z[v];
        int g = batch[v];
        float w = dv * dv;
        atomicAdd(&t[wv][g * 2],     w * zv.x);
        atomicAdd(&t[wv][g * 2 + 1], w * zv.y);
        atomicAdd(&scnt[wv][g], 1);
    }
    __syncthreads();
    if (tid < NGRAPH * 2) {
        float s = t[0][tid] + t[1][tid] + t[2][tid] + t[3][tid];
        if (s != 0.f) atomicAdd(&tsum[tid], s);
    }
    if (tid < NGRAPH) {
        int s = scnt[0][tid] + scnt[1][tid] + scnt[2][tid] + scnt[3][tid];
        if (s) atomicAdd(&cnt[tid], s);
    }
}

__global__ void k_classify(const float* __restrict__ tsum, const int* __restrict__ cnt,
                           const float* __restrict__ beff, const float* __restrict__ bc,
                           float* __restrict__ out) {
    int t = threadIdx.x;
    if (t >= NGRAPH * 2) return;
    int g = t >> 1, c = t & 1;
    int cg = cnt[g];
    out[t] = cg ? (tsum[t] / (float)cg + beff[c]) : bc[c];
}

// ---------------- launch ----------------

extern "C" void kernel_launch(void* const* d_in, const int* in_sizes, int n_in,
                              void* d_out, int out_size, void* d_ws, size_t ws_size,
                              hipStream_t stream) {
    const float* x    = (const float*)d_in[0];
    const int*   ei   = (const int*)d_in[1];
    const int*   batch= (const int*)d_in[2];
    const float* W1   = (const float*)d_in[3];
    const float* b1   = (const float*)d_in[4];
    const float* W2   = (const float*)d_in[5];
    const float* b2   = (const float*)d_in[6];
    const float* Wc   = (const float*)d_in[7];
    const float* bc   = (const float*)d_in[8];

    const int n = in_sizes[0] / D;       // 100000
    const int E = in_sizes[1] / 2;       // 3200000
    const int* src = ei;
    const int* dst = ei + E;
    const int nb = (n + WINSZ - 1) / WINSZ;   // 391 dst-windows

    char* ws = (char*)d_ws;
    size_t off = 0;
    auto carve = [&](size_t bytes) -> char* {
        char* p = ws + off;
        off = (off + bytes + 255) & ~(size_t)255;
        return p;
    };
    unsigned short* bufBF = (unsigned short*)carve((size_t)n * D * 2);   // xW1 (bf16)
    float2* z     = (float2*)carve((size_t)n * 8);                       // projected h1
    unsigned* ebuf= (unsigned*)carve((size_t)nb * WINSLOTS * 4);         // windowed edges
    int*   csr    = (int*)  carve((size_t)nb * WINSLOTS * 4);            // windowed CSR
    // zero-region: cursor | tsum | cnt
    const int zero_words = 512 + NGRAPH * 2 + NGRAPH;
    int*   cursor = (int*)  carve(zero_words * 4);
    float* tsum   = (float*)(cursor + 512);
    int*   cnt    = (int*)  (tsum + NGRAPH * 2);
    int2*  offcnt = (int2*) carve((size_t)n * 8);
    float* dinv   = (float*)carve((size_t)n * 4);
    float* Weff   = (float*)carve(D * 2 * 4);
    float* beff   = (float*)carve(2 * 4);
    unsigned short* W1bfT = (unsigned short*)carve(D * D * 2);

    hipMemsetAsync(cursor, 0, zero_words * 4, stream);

    // CSR build (windowed counting sort, re-read two-phase)
    k_part<<<(E + PBCHUNK - 1) / PBCHUNK, 256, 0, stream>>>(src, dst, cursor, ebuf, E, nb);
    k_csrwin<<<nb, 256, 0, stream>>>(ebuf, cursor, csr, offcnt, dinv, n);
    k_prep<<<1, 256, 0, stream>>>(W1, W2, Wc, b2, bc, Weff, beff, W1bfT);

    // layer 1 GEMM (MFMA bf16, BM=128): xW1 -> bufBF
    k_gemm_mfma<<<(n + GBM - 1) / GBM, 256, 0, stream>>>(x, W1bfT, bufBF, n);
    // layer-1 agg + relu + project to z
    k_agg_proj<<<(n + 3) / 4, 256, 0, stream>>>(bufBF, offcnt, csr, dinv, b1, Weff, z, n);

    // fused layer-2 agg + mean-pool on z (raw edge stream)
    k_pool_edges<<<POOLBLK, 256, 0, stream>>>(z, src, dst, dinv, batch, tsum, cnt, n, E);
    k_classify<<<1, 128, 0, stream>>>(tsum, cnt, beff, bc, (float*)d_out);
}

// Round 13
// 299.315 us; speedup vs baseline: 1.0975x; 1.0975x over previous
//
#include <hip/hip_runtime.h>
#include <hip/hip_bf16.h>

#define D 128
#define NGRAPH 64
#define POOLBLK 256     // blocks in k_pool_edges
#define PBCHUNK 4096    // edges per block in k_part
#define WINSZ 256       // nodes per dst-window
#define WINSLOTS 16384  // edge slots per window (mean ~8184, 2x headroom)
#define XP 136          // padded LDS row (bf16) -> 2-way bank aliasing only

typedef __attribute__((ext_vector_type(4))) float f32x4;
typedef __attribute__((ext_vector_type(8))) short bf16x8;

__device__ __forceinline__ unsigned short f2bf(float f) {
    union { float f; unsigned int i; } u; u.f = f;
    unsigned int r = u.i + 0x7fffu + ((u.i >> 16) & 1u);   // round-to-nearest-even
    return (unsigned short)(r >> 16);
}
__device__ __forceinline__ float2 bf2_to_f2(unsigned int u) {
    union { unsigned int i; float f; } a, b;
    a.i = u << 16;            // low ushort  = element 0
    b.i = u & 0xffff0000u;    // high ushort = element 1
    return make_float2(a.f, b.f);
}

// ---------------- prep: Weff = W2@Wc, beff, and zero cursor/tsum/cnt -----

__global__ __launch_bounds__(256) void k_prep(const float* __restrict__ W2,
                                              const float* __restrict__ Wc,
                                              const float* __restrict__ b2,
                                              const float* __restrict__ bc,
                                              float* __restrict__ Weff,
                                              float* __restrict__ beff,
                                              int* __restrict__ zero_region,
                                              int zero_words) {
    int t = threadIdx.x;
    int i = t >> 1, c = t & 1;
    float acc = 0.f;
    for (int k = 0; k < D; ++k) acc += W2[i * D + k] * Wc[k * 2 + c];
    Weff[i * 2 + c] = acc;
    if (i == 0) {
        float s = 0.f;
        for (int k = 0; k < D; ++k) s += b2[k] * Wc[k * 2 + c];
        beff[c] = s + bc[c];
    }
    for (int j = t; j < zero_words; j += 256) zero_region[j] = 0;
}

// ---------------- CSR build: windowed counting sort ----------------------

__global__ __launch_bounds__(256) void k_part(const int* __restrict__ src,
                                              const int* __restrict__ dst,
                                              int* __restrict__ cursor,
                                              unsigned* __restrict__ ebuf,
                                              int E, int nb) {
    __shared__ unsigned spack[PBCHUNK];
    __shared__ unsigned short sbin[PBCHUNK];
    __shared__ unsigned short slrank[PBCHUNK];
    __shared__ int hist[400];
    __shared__ int base[400];
    int tid = threadIdx.x;
    for (int i = tid; i < nb; i += 256) hist[i] = 0;
    __syncthreads();
    int b0 = blockIdx.x * PBCHUNK;
    int cnt = min(PBCHUNK, E - b0);
    for (int j = tid; j < cnt; j += 256) {
        int s = __builtin_nontemporal_load(&src[b0 + j]);
        int d = __builtin_nontemporal_load(&dst[b0 + j]);
        int bin = d >> 8;
        spack[j] = (unsigned)s | ((unsigned)(d & 255) << 17);
        sbin[j] = (unsigned short)bin;
        slrank[j] = (unsigned short)atomicAdd(&hist[bin], 1);
    }
    __syncthreads();
    for (int i = tid; i < nb; i += 256)
        base[i] = hist[i] ? atomicAdd(&cursor[i], hist[i]) : 0;
    __syncthreads();
    for (int j = tid; j < cnt; j += 256) {
        int bin = sbin[j];
        ebuf[(size_t)bin * WINSLOTS + base[bin] + slrank[j]] = spack[j];
    }
}

__global__ __launch_bounds__(256) void k_csrwin(const unsigned* __restrict__ ebuf,
                                                const int* __restrict__ cursor,
                                                int* __restrict__ csr,
                                                int2* __restrict__ offcnt,
                                                float* __restrict__ dinv, int n) {
    __shared__ int hist[WINSZ];
    __shared__ int lscan[WINSZ];
    __shared__ int sexcl[WINSZ];
    int b = blockIdx.x;
    int tid = threadIdx.x;
    hist[tid] = 0;
    __syncthreads();
    int cnt = cursor[b];
    const unsigned* eb = ebuf + (size_t)b * WINSLOTS;
    for (int j = tid; j < cnt; j += 256)
        atomicAdd(&hist[eb[j] >> 17], 1);
    __syncthreads();
    int deg = hist[tid];
    lscan[tid] = deg;
    __syncthreads();
    for (int off = 1; off < 256; off <<= 1) {
        int y = (tid >= off) ? lscan[tid - off] : 0;
        __syncthreads();
        lscan[tid] += y;
        __syncthreads();
    }
    int excl = lscan[tid] - deg;
    int v = b * WINSZ + tid;
    int gbase = b * WINSLOTS;
    if (v < n) {
        offcnt[v] = make_int2(gbase + excl, deg);
        dinv[v] = rsqrtf((float)(deg + 1));
    }
    hist[tid] = 0;
    sexcl[tid] = excl;
    __syncthreads();
    for (int j = tid; j < cnt; j += 256) {
        unsigned p = eb[j];
        int d8 = (int)(p >> 17);
        int lr = atomicAdd(&hist[d8], 1);
        csr[gbase + sexcl[d8] + lr] = (int)(p & 0x1FFFFu);
    }
}

// ---------------- MFMA bf16 GEMM: H' = (bf16(X) @ bf16(W1)) * dinv[row] ---
// W1 (fp32, row-major [k][n]) converted+transposed into LDS in-kernel.
// A frag (16x16x32): lane l -> row=l&15, k=8*(l>>4)+j ; B: col=l&15, k same
// C/D: col=lane&15, row=4*(lane>>4)+reg   [m89-verified]

__global__ __launch_bounds__(256) void k_gemm_mfma(const float* __restrict__ X,
                                                   const float* __restrict__ W1,
                                                   const float* __restrict__ dinv,
                                                   unsigned short* __restrict__ H, int nrows) {
    __shared__ unsigned short xs[64][XP];    // X tile, bf16
    __shared__ unsigned short wt[128][XP];   // W^T: wt[n][k]
    int tid = threadIdx.x;
    int m0 = blockIdx.x * 64;
    // stage W^T: coalesced fp32 read of W1 row k, scattered LDS writes
    for (int i = tid; i < 2048; i += 256) {
        int elt = i * 8;
        int k = elt >> 7, n0 = elt & 127;            // W1[k][n0..n0+7]
        float4 a = *(const float4*)&W1[k * D + n0];
        float4 b = *(const float4*)&W1[k * D + n0 + 4];
        wt[n0 + 0][k] = f2bf(a.x); wt[n0 + 1][k] = f2bf(a.y);
        wt[n0 + 2][k] = f2bf(a.z); wt[n0 + 3][k] = f2bf(a.w);
        wt[n0 + 4][k] = f2bf(b.x); wt[n0 + 5][k] = f2bf(b.y);
        wt[n0 + 6][k] = f2bf(b.z); wt[n0 + 7][k] = f2bf(b.w);
    }
    // stage X tile (convert fp32 -> bf16)
    for (int i = tid; i < 2048; i += 256) {
        int elt = i * 4;
        int r = elt >> 7, c = elt & 127;
        int gr = m0 + r;
        float4 v = (gr < nrows) ? *(const float4*)&X[(size_t)gr * D + c]
                                : make_float4(0.f, 0.f, 0.f, 0.f);
        ushort4 bv;
        bv.x = f2bf(v.x); bv.y = f2bf(v.y); bv.z = f2bf(v.z); bv.w = f2bf(v.w);
        *(ushort4*)&xs[r][c] = bv;
    }
    __syncthreads();
    int wv = tid >> 6, lane = tid & 63;
    int lrow = lane & 15, lk = (lane >> 4) * 8;
    f32x4 acc[8];
#pragma unroll
    for (int i = 0; i < 8; ++i) acc[i] = (f32x4){0.f, 0.f, 0.f, 0.f};
#pragma unroll
    for (int kk = 0; kk < 128; kk += 32) {
        bf16x8 a = *(bf16x8*)&xs[wv * 16 + lrow][kk + lk];
#pragma unroll
        for (int nt = 0; nt < 8; ++nt) {
            bf16x8 b = *(bf16x8*)&wt[nt * 16 + lrow][kk + lk];
            acc[nt] = __builtin_amdgcn_mfma_f32_16x16x32_bf16(a, b, acc[nt], 0, 0, 0);
        }
    }
    int orow = m0 + wv * 16 + (lane >> 4) * 4;
    float dvr[4];
#pragma unroll
    for (int r = 0; r < 4; ++r) dvr[r] = (orow + r < nrows) ? dinv[orow + r] : 0.f;
#pragma unroll
    for (int nt = 0; nt < 8; ++nt) {
#pragma unroll
        for (int r = 0; r < 4; ++r) {
            int gr = orow + r;
            if (gr < nrows) H[(size_t)gr * D + nt * 16 + lrow] = f2bf(acc[nt][r] * dvr[r]);
        }
    }
}

// ---------------- layer-1 agg + relu + projection --------------------------
// H is pre-scaled by dinv[src]:  agg(v) = dv * (H'[v] + sum_e H'[s_e])
// Edge loop = pure unweighted row sum (no per-edge dinv gather / multiply).

__global__ __launch_bounds__(256) void k_agg_proj(const unsigned short* __restrict__ H,
                                                  const int2* __restrict__ offcnt,
                                                  const int* __restrict__ csr,
                                                  const float* __restrict__ dinv,
                                                  const float* __restrict__ bias,
                                                  const float* __restrict__ Weff,
                                                  float2* __restrict__ z, int n) {
    int wid = threadIdx.x >> 6;
    int lane = threadIdx.x & 63;
    int v = blockIdx.x * 4 + wid;
    if (v >= n) return;
    float dv = dinv[v];
    int l2 = lane * 2;
    unsigned us = *(const unsigned*)(H + (size_t)v * D + l2);
    float2 hs = bf2_to_f2(us);
    float2 acc = make_float2(hs.x, hs.y);     // self term: H'[v]
    int2 oc = offcnt[v];
    int e = oc.x, eE = oc.x + oc.y;
    for (; e + 7 < eE; e += 8) {
        int s[8];
#pragma unroll
        for (int j = 0; j < 8; ++j) s[j] = csr[e + j];
        unsigned u[8];
#pragma unroll
        for (int j = 0; j < 8; ++j) u[j] = *(const unsigned*)(H + (size_t)s[j] * D + l2);
#pragma unroll
        for (int j = 0; j < 8; ++j) {
            float2 h = bf2_to_f2(u[j]);
            acc.x += h.x; acc.y += h.y;
        }
    }
    for (; e + 3 < eE; e += 4) {
        int s0 = csr[e], s1 = csr[e + 1], s2 = csr[e + 2], s3 = csr[e + 3];
        unsigned u0 = *(const unsigned*)(H + (size_t)s0 * D + l2);
        unsigned u1 = *(const unsigned*)(H + (size_t)s1 * D + l2);
        unsigned u2 = *(const unsigned*)(H + (size_t)s2 * D + l2);
        unsigned u3 = *(const unsigned*)(H + (size_t)s3 * D + l2);
        float2 h0 = bf2_to_f2(u0), h1 = bf2_to_f2(u1);
        float2 h2 = bf2_to_f2(u2), h3 = bf2_to_f2(u3);
        acc.x += h0.x + h1.x + h2.x + h3.x;
        acc.y += h0.y + h1.y + h2.y + h3.y;
    }
    for (; e < eE; ++e) {
        int s0 = csr[e];
        unsigned u0 = *(const unsigned*)(H + (size_t)s0 * D + l2);
        float2 h0 = bf2_to_f2(u0);
        acc.x += h0.x; acc.y += h0.y;
    }
    float2 b = ((const float2*)bias)[lane];
    acc.x = fmaxf(acc.x * dv + b.x, 0.f);
    acc.y = fmaxf(acc.y * dv + b.y, 0.f);
    float4 wv = *(const float4*)&Weff[l2 * 2];
    float z0 = acc.x * wv.x + acc.y * wv.z;
    float z1 = acc.x * wv.y + acc.y * wv.w;
#pragma unroll
    for (int off = 32; off >= 1; off >>= 1) {
        z0 += __shfl_xor(z0, off, 64);
        z1 += __shfl_xor(z1, off, 64);
    }
    if (lane == 0) z[v] = make_float2(z0, z1);
}

// ---------------- fused layer-2 agg + mean-pool on projected z -----------
// per-wave private LDS accumulators (4x less same-address contention)

__global__ __launch_bounds__(256) void k_pool_edges(const float2* __restrict__ z,
                                                    const int* __restrict__ src,
                                                    const int* __restrict__ dst,
                                                    const float* __restrict__ dinv,
                                                    const int* __restrict__ batch,
                                                    float* __restrict__ tsum,
                                                    int* __restrict__ cnt,
                                                    int n, int E) {
    __shared__ float t[4][NGRAPH * 2];
    __shared__ int scnt[4][NGRAPH];
    int tid = threadIdx.x;
    int wv = tid >> 6;
    for (int j = tid; j < 4 * NGRAPH * 2; j += 256) ((float*)t)[j] = 0.f;
    for (int j = tid; j < 4 * NGRAPH; j += 256) ((int*)scnt)[j] = 0;
    __syncthreads();

    int i = (blockIdx.x * 256 + tid) * 4;
    int stride = POOLBLK * 256 * 4;
    for (; i < E; i += stride) {
        if (i + 3 < E) {
            int4 s4 = *(const int4*)&src[i];
            int4 d4 = *(const int4*)&dst[i];
            float w0 = dinv[s4.x] * dinv[d4.x];
            float w1 = dinv[s4.y] * dinv[d4.y];
            float w2 = dinv[s4.z] * dinv[d4.z];
            float w3 = dinv[s4.w] * dinv[d4.w];
            float2 z0 = z[s4.x], z1 = z[s4.y], z2 = z[s4.z], z3 = z[s4.w];
            int g0 = batch[d4.x], g1 = batch[d4.y], g2 = batch[d4.z], g3 = batch[d4.w];
            atomicAdd(&t[wv][g0 * 2],     w0 * z0.x);
            atomicAdd(&t[wv][g0 * 2 + 1], w0 * z0.y);
            atomicAdd(&t[wv][g1 * 2],     w1 * z1.x);
            atomicAdd(&t[wv][g1 * 2 + 1], w1 * z1.y);
            atomicAdd(&t[wv][g2 * 2],     w2 * z2.x);
            atomicAdd(&t[wv][g2 * 2 + 1], w2 * z2.y);
            atomicAdd(&t[wv][g3 * 2],     w3 * z3.x);
            atomicAdd(&t[wv][g3 * 2 + 1], w3 * z3.y);
        } else {
            for (int j = i; j < E; ++j) {
                int s = src[j], d = dst[j];
                float w = dinv[s] * dinv[d];
                float2 zv = z[s];
                int g = batch[d];
                atomicAdd(&t[wv][g * 2],     w * zv.x);
                atomicAdd(&t[wv][g * 2 + 1], w * zv.y);
            }
        }
    }
    for (int v = blockIdx.x * 256 + tid; v < n; v += POOLBLK * 256) {
        float dv = dinv[v];
        float2 zv = z[v];
        int g = batch[v];
        float w = dv * dv;
        atomicAdd(&t[wv][g * 2],     w * zv.x);
        atomicAdd(&t[wv][g * 2 + 1], w * zv.y);
        atomicAdd(&scnt[wv][g], 1);
    }
    __syncthreads();
    if (tid < NGRAPH * 2) {
        float s = t[0][tid] + t[1][tid] + t[2][tid] + t[3][tid];
        if (s != 0.f) atomicAdd(&tsum[tid], s);
    }
    if (tid < NGRAPH) {
        int s = scnt[0][tid] + scnt[1][tid] + scnt[2][tid] + scnt[3][tid];
        if (s) atomicAdd(&cnt[tid], s);
    }
}

__global__ void k_classify(const float* __restrict__ tsum, const int* __restrict__ cnt,
                           const float* __restrict__ beff, const float* __restrict__ bc,
                           float* __restrict__ out) {
    int t = threadIdx.x;
    if (t >= NGRAPH * 2) return;
    int g = t >> 1, c = t & 1;
    int cg = cnt[g];
    out[t] = cg ? (tsum[t] / (float)cg + beff[c]) : bc[c];
}

// ---------------- launch ----------------

extern "C" void kernel_launch(void* const* d_in, const int* in_sizes, int n_in,
                              void* d_out, int out_size, void* d_ws, size_t ws_size,
                              hipStream_t stream) {
    const float* x    = (const float*)d_in[0];
    const int*   ei   = (const int*)d_in[1];
    const int*   batch= (const int*)d_in[2];
    const float* W1   = (const float*)d_in[3];
    const float* b1   = (const float*)d_in[4];
    const float* W2   = (const float*)d_in[5];
    const float* b2   = (const float*)d_in[6];
    const float* Wc   = (const float*)d_in[7];
    const float* bc   = (const float*)d_in[8];

    const int n = in_sizes[0] / D;       // 100000
    const int E = in_sizes[1] / 2;       // 3200000
    const int* src = ei;
    const int* dst = ei + E;
    const int nb = (n + WINSZ - 1) / WINSZ;   // 391 dst-windows

    char* ws = (char*)d_ws;
    size_t off = 0;
    auto carve = [&](size_t bytes) -> char* {
        char* p = ws + off;
        off = (off + bytes + 255) & ~(size_t)255;
        return p;
    };
    unsigned short* bufBF = (unsigned short*)carve((size_t)n * D * 2);   // H' (bf16, dinv-scaled)
    float2* z     = (float2*)carve((size_t)n * 8);                       // projected h1
    unsigned* ebuf= (unsigned*)carve((size_t)nb * WINSLOTS * 4);         // windowed edges
    int*   csr    = (int*)  carve((size_t)nb * WINSLOTS * 4);            // windowed CSR
    // zero-region: cursor | tsum | cnt  (zeroed by k_prep)
    const int zero_words = 512 + NGRAPH * 2 + NGRAPH;
    int*   cursor = (int*)  carve(zero_words * 4);
    float* tsum   = (float*)(cursor + 512);
    int*   cnt    = (int*)  (tsum + NGRAPH * 2);
    int2*  offcnt = (int2*) carve((size_t)n * 8);
    float* dinv   = (float*)carve((size_t)n * 4);
    float* Weff   = (float*)carve(D * 2 * 4);
    float* beff   = (float*)carve(2 * 4);

    // prep (Weff/beff + zeroing) then CSR build
    k_prep<<<1, 256, 0, stream>>>(W2, Wc, b2, bc, Weff, beff, cursor, zero_words);
    k_part<<<(E + PBCHUNK - 1) / PBCHUNK, 256, 0, stream>>>(src, dst, cursor, ebuf, E, nb);
    k_csrwin<<<nb, 256, 0, stream>>>(ebuf, cursor, csr, offcnt, dinv, n);

    // layer 1 GEMM (MFMA bf16, in-kernel W1 conversion), output scaled by dinv
    k_gemm_mfma<<<(n + 63) / 64, 256, 0, stream>>>(x, W1, dinv, bufBF, n);
    // layer-1 agg (unweighted sum of pre-scaled rows) + relu + project to z
    k_agg_proj<<<(n + 3) / 4, 256, 0, stream>>>(bufBF, offcnt, csr, dinv, b1, Weff, z, n);

    // fused layer-2 agg + mean-pool on z (raw edge stream)
    k_pool_edges<<<POOLBLK, 256, 0, stream>>>(z, src, dst, dinv, batch, tsum, cnt, n, E);
    k_classify<<<1, 128, 0, stream>>>(tsum, cnt, beff, bc, (float*)d_out);
}